// Round 11
// baseline (1184.047 us; speedup 1.0000x reference)
//
#include <hip/hip_runtime.h>
#include <hip/hip_bf16.h>
#include <stdint.h>

// Problem constants
#define BB 2
#define SS 2048
#define DD 4096
#define HH 32
#define HDD 128

typedef unsigned short u16;
typedef unsigned int u32;

constexpr float CLIPV  = 8.0f;
constexpr float LN_EPS_ = 1e-5f;
constexpr float SCALE_ = 0.08838834764831845f;   // 1/sqrt(128)
constexpr float LOG2E_ = 1.4426950408889634f;

using f32x4  = __attribute__((ext_vector_type(4))) float;
using f32x16 = __attribute__((ext_vector_type(16))) float;
using s16x8  = __attribute__((ext_vector_type(8))) short;

__device__ inline u16 f2bf(float f) {
  union { float f; u32 u; } v; v.f = f;
  u32 r = (v.u + 0x7FFFu + ((v.u >> 16) & 1u)) >> 16;
  return (u16)r;
}
__device__ inline float bf2f(u16 u) {
  union { u32 u; float f; } v; v.u = ((u32)u) << 16;
  return v.f;
}

typedef __attribute__((address_space(1))) void gvoid;
typedef __attribute__((address_space(3))) void lvoid;
__device__ inline void gload_lds16(const void* g, void* l) {
  __builtin_amdgcn_global_load_lds((gvoid*)g, (lvoid*)l, 16, 0, 0);
}

__device__ inline f32x4 mfma16(s16x8 a, s16x8 b, f32x4 c) {
  return __builtin_amdgcn_mfma_f32_16x16x32_bf16(a, b, c, 0, 0, 0);
}
__device__ inline f32x16 mfma32(s16x8 a, s16x8 b, f32x16 c) {
  return __builtin_amdgcn_mfma_f32_32x32x16_bf16(a, b, c, 0, 0, 0);
}

// ---------------- kernel 1: f32 -> bf16 elementwise ----------------
__global__ void k_cvt_bf16(const float* __restrict__ in, u16* __restrict__ out, int nvec) {
  int i = blockIdx.x * 256 + threadIdx.x;
  if (i >= nvec) return;
  float4 a = ((const float4*)in)[i * 2];
  float4 b = ((const float4*)in)[i * 2 + 1];
  u16 tmp[8];
  tmp[0] = f2bf(a.x); tmp[1] = f2bf(a.y); tmp[2] = f2bf(a.z); tmp[3] = f2bf(a.w);
  tmp[4] = f2bf(b.x); tmp[5] = f2bf(b.y); tmp[6] = f2bf(b.z); tmp[7] = f2bf(b.w);
  ((uint4*)out)[i] = *(const uint4*)tmp;
}

// ---------------- kernel 2: transpose + convert: src f32 [R][C] -> dst bf16 [C][R] ----------------
__global__ void k_transpose_cvt(const float* __restrict__ src, u16* __restrict__ dst, int R, int C) {
  __shared__ float tile[32][33];
  int c0 = blockIdx.x * 32, r0 = blockIdx.y * 32;
  int tx = threadIdx.x & 31, ty = threadIdx.x >> 5;   // 32 x 8
  #pragma unroll
  for (int i = 0; i < 32; i += 8)
    tile[ty + i][tx] = src[(size_t)(r0 + ty + i) * C + (c0 + tx)];
  __syncthreads();
  #pragma unroll
  for (int i = 0; i < 32; i += 8)
    dst[(size_t)(c0 + ty + i) * R + (r0 + tx)] = f2bf(tile[tx][ty + i]);
}

// ---------------- 256x256 GEMM, 32x32x16 MFMA + asm ds_read + counted lgkm ----------------
// Round-8 winning skeleton (compiler-invisible ds_read_b128, counted lgkm, same
// phase ledger/staging/vmcnt), upgraded to 32x32x16 MFMA: half the MFMA instrs,
// ~17% less matrix-pipe time (2495 vs 2176 TF ubench ceiling).
// Per wave: 128x64 out = 4 Mtiles(32) x 2 Ntiles(32); acc f32x16[4][2].
// A/B frag: row=lane&31, k=(lane>>5)*8+j per 16-k chunk kc (0..3 per BK=64).
__device__ __forceinline__ void stage_half(u16* ldsHalf, const u16* g, int K, int tid) {
  #pragma unroll
  for (int it = 0; it < 2; ++it) {
    int p = (it << 9) + tid;           // 16B slot index 0..1023
    int row = p >> 3;                  // 0..127
    int slotk = (p & 7) ^ (row & 7);   // inverse-swizzled source slot
    gload_lds16(g + (size_t)row * K + (slotk << 3), ldsHalf + ((size_t)p << 3));
  }
}

#define DSR(dst, adr, IMM) \
  asm volatile("ds_read_b128 %0, %1 offset:" #IMM : "=v"(dst) : "v"(adr) : "memory")

// A mtiles {0,1} (imm 0 / 4096 = 32 rows)  [8 reads]
#define RD_A01(k0, k1, k2, k3)       \
  DSR(aC[0][0], k0, 0);              \
  DSR(aC[0][1], k1, 0);              \
  DSR(aC[0][2], k2, 0);              \
  DSR(aC[0][3], k3, 0);              \
  DSR(aC[1][0], k0, 4096);           \
  DSR(aC[1][1], k1, 4096);           \
  DSR(aC[1][2], k2, 4096);           \
  DSR(aC[1][3], k3, 4096);

// A mtiles {2,3} (imm 8192 / 12288)  [8 reads]
#define RD_A23(k0, k1, k2, k3)       \
  DSR(aN[0][0], k0, 8192);           \
  DSR(aN[0][1], k1, 8192);           \
  DSR(aN[0][2], k2, 8192);           \
  DSR(aN[0][3], k3, 8192);           \
  DSR(aN[1][0], k0, 12288);          \
  DSR(aN[1][1], k1, 12288);          \
  DSR(aN[1][2], k2, 12288);          \
  DSR(aN[1][3], k3, 12288);

// B ntile 0 (imm 0)  [4 reads]
#define RD_BN0(k0, k1, k2, k3)       \
  DSR(bA_[0], k0, 0);                \
  DSR(bA_[1], k1, 0);                \
  DSR(bA_[2], k2, 0);                \
  DSR(bA_[3], k3, 0);

// B ntile 1 (imm 4096)  [4 reads]
#define RD_BN1(k0, k1, k2, k3)       \
  DSR(bB_[0], k0, 4096);             \
  DSR(bB_[1], k1, 4096);             \
  DSR(bB_[2], k2, 4096);             \
  DSR(bB_[3], k3, 4096);

#define LGKM(N)                                                    \
  asm volatile("s_waitcnt lgkmcnt(" #N ")" ::: "memory");          \
  __builtin_amdgcn_sched_barrier(0);

// 8 MFMA: mtiles {MB, MB+1} x ntile NT over kc 0..3 (kc outer -> 2 indep chains)
#define MQ32(AF, BF, MB, NT)                                                  \
  _Pragma("unroll")                                                           \
  for (int kc_ = 0; kc_ < 4; ++kc_) {                                         \
    acc[(MB)][NT]     = mfma32(AF[0][kc_], BF[kc_], acc[(MB)][NT]);           \
    acc[(MB) + 1][NT] = mfma32(AF[1][kc_], BF[kc_], acc[(MB) + 1][NT]);       \
  }

template <int EPI>   // 0: clip to +-8, store bf16 ; 1: store f32
__launch_bounds__(512)
__global__ void k_gemm256(const u16* __restrict__ A, const u16* __restrict__ Bt,
                          void* __restrict__ Cout, int M, int N, int K, int nBY) {
  __shared__ u16 lds[65536];            // A: bytes [0,65536) ; B: [65536,131072)
  u16* sA = lds;
  u16* sB = lds + 32768;
  const int tid = threadIdx.x;
  const int lane = tid & 63, w = tid >> 6;
  const int wm = w >> 2, wn = w & 3;          // 2 x 4 waves
  const int r31 = lane & 31, g32 = lane >> 5, e7 = lane & 7;

  // column-major-within-XCD bijective swizzle (nwg % 8 == 0)
  const int nwg = gridDim.x;
  const int cpx = nwg >> 3;
  const int id2 = (blockIdx.x & 7) * cpx + (blockIdx.x >> 3);
  const int bx = id2 / nBY, by = id2 % nBY;
  const int m0 = by * 256, n0 = bx * 256;

  const int NT = K >> 6;
  const u16* gA = A  + (size_t)m0 * K;
  const u16* gB = Bt + (size_t)n0 * K;

  // byte addresses (buf0) per k-chunk kc; buffer toggle ^32768
  u32 aBs[4], bBs[4];
  #pragma unroll
  for (int kc = 0; kc < 4; ++kc) {
    int slot = ((kc << 1) | g32) ^ e7;
    aBs[kc] = (u32)(wm * 16384 + r31 * 128 + slot * 16);
    bBs[kc] = (u32)(65536 + (wn >> 1) * 16384 + (wn & 1) * 8192 + r31 * 128 + slot * 16);
  }

  f32x16 acc[4][2];
  #pragma unroll
  for (int i = 0; i < 4; ++i)
    #pragma unroll
    for (int j = 0; j < 2; ++j)
      #pragma unroll
      for (int r = 0; r < 16; ++r) acc[i][j][r] = 0.f;

  // ---- prologue: 7 half-tiles; drain; pre-issue A{mt01}(0), B{n0}(0) reads ----
  stage_half(sA,         gA,                        K, tid);  // Ah0(0)
  stage_half(sA + 8192,  gA + (size_t)128 * K,      K, tid);  // Ah1(0)
  stage_half(sB,         gB,                        K, tid);  // Bh0(0)
  stage_half(sB + 8192,  gB + (size_t)128 * K,      K, tid);  // Bh1(0)
  stage_half(sB + 16384, gB + 64,                   K, tid);  // Bh0(1)
  stage_half(sB + 24576, gB + (size_t)128 * K + 64, K, tid);  // Bh1(1)
  stage_half(sA + 24576, gA + (size_t)128 * K + 64, K, tid);  // Ah1(1)
  asm volatile("s_waitcnt vmcnt(0)" ::: "memory");
  __builtin_amdgcn_s_barrier();

  s16x8 aC[2][4], aN[2][4], bA_[4], bB_[4];
  RD_A01(aBs[0], aBs[1], aBs[2], aBs[3])
  RD_BN0(bBs[0], bBs[1], bBs[2], bBs[3])

  for (int t = 0; t < NT; ++t) {
    const int d = t & 1;
    const bool m1 = (t + 1 < NT);
    const bool m2 = (t + 2 < NT);
    const u32 dx = d ? 32768u : 0u;
    const u32 aD0 = aBs[0] ^ dx, aD1 = aBs[1] ^ dx, aD2 = aBs[2] ^ dx, aD3 = aBs[3] ^ dx;
    const u32 bD0 = bBs[0] ^ dx, bD1 = bBs[1] ^ dx, bD2 = bBs[2] ^ dx, bD3 = bBs[3] ^ dx;
    const u32 aX0 = aD0 ^ 32768u, aX1 = aD1 ^ 32768u, aX2 = aD2 ^ 32768u, aX3 = aD3 ^ 32768u;
    const u32 bX0 = bD0 ^ 32768u, bX1 = bD1 ^ 32768u, bX2 = bD2 ^ 32768u, bX3 = bD3 ^ 32768u;

    // ---------- P1: issue B{n1}(t); stage Ah0(t+1); wait(4); mt01 x n0 ----------
    RD_BN1(bD0, bD1, bD2, bD3)
    if (m1) stage_half(sA + (d ^ 1) * 16384, gA + (size_t)(t + 1) * 64, K, tid);
    LGKM(4)
    __builtin_amdgcn_s_setprio(1);
    MQ32(aC, bA_, 0, 0)
    __builtin_amdgcn_s_setprio(0);
    __builtin_amdgcn_s_barrier();

    // ---------- P2: issue A{mt23}(t); stage Bh0(t+2); wait(8); mt01 x n1 ----------
    RD_A23(aD0, aD1, aD2, aD3)
    if (m2) stage_half(sB + d * 16384, gB + (size_t)(t + 2) * 64, K, tid);
    LGKM(8)
    __builtin_amdgcn_s_setprio(1);
    MQ32(aC, bB_, 0, 1)
    __builtin_amdgcn_s_setprio(0);
    __builtin_amdgcn_s_barrier();

    // ---------- P3: stage Bh1(t+2); wait(0); mt23 x n0; gate vmcnt(4) ----------
    if (m2) stage_half(sB + d * 16384 + 8192, gB + (size_t)128 * K + (size_t)(t + 2) * 64, K, tid);
    LGKM(0)
    __builtin_amdgcn_s_setprio(1);
    MQ32(aN, bA_, 2, 0)
    __builtin_amdgcn_s_setprio(0);
    if (m2) { asm volatile("s_waitcnt vmcnt(4)" ::: "memory"); }
    else    { asm volatile("s_waitcnt vmcnt(0)" ::: "memory"); }
    __builtin_amdgcn_s_barrier();

    // ---------- P4: issue A{mt01},B{n0}(t+1); stage Ah1(t+2); mt23 x n1; gate vmcnt(2) ----------
    if (m1) {
      RD_A01(aX0, aX1, aX2, aX3)
      RD_BN0(bX0, bX1, bX2, bX3)
      if (m2) stage_half(sA + d * 16384 + 8192, gA + (size_t)128 * K + (size_t)(t + 2) * 64, K, tid);
    }
    __builtin_amdgcn_sched_barrier(0);
    __builtin_amdgcn_s_setprio(1);
    MQ32(aN, bB_, 2, 1)
    __builtin_amdgcn_s_setprio(0);
    if (m2) { asm volatile("s_waitcnt vmcnt(2)" ::: "memory"); }
    else    { asm volatile("s_waitcnt vmcnt(0)" ::: "memory"); }
    __builtin_amdgcn_s_barrier();
  }

  // epilogue: C/D 32x32 layout col=lane&31, row=(r&3)+8*(r>>2)+4*(lane>>5)
  #pragma unroll
  for (int mt = 0; mt < 4; ++mt)
    #pragma unroll
    for (int nt = 0; nt < 2; ++nt)
      #pragma unroll
      for (int r = 0; r < 16; ++r) {
        int m = m0 + wm * 128 + mt * 32 + (r & 3) + 8 * (r >> 2) + 4 * g32;
        int n = n0 + wn * 64 + nt * 32 + r31;
        float v = acc[mt][nt][r];
        if (EPI == 0) {
          v = fminf(fmaxf(v, -CLIPV), CLIPV);
          ((u16*)Cout)[(size_t)m * N + n] = f2bf(v);
        } else {
          ((float*)Cout)[(size_t)m * N + n] = v;
        }
      }
}

// ---------------- kernel 4: LN(q), LN(k) over D=4096 + head relayout of q,k ----------------
__device__ inline void unpack8(uint4 u, float* f) {
  const u16* p = (const u16*)&u;
  #pragma unroll
  for (int j = 0; j < 8; ++j) f[j] = bf2f(p[j]);
}

__global__ void k_ln_reorder(const u16* __restrict__ qkv,
                             const float* __restrict__ qw, const float* __restrict__ qb,
                             const float* __restrict__ kw, const float* __restrict__ kb,
                             u16* __restrict__ Qo, u16* __restrict__ Ko) {
  const int row = blockIdx.x;               // 0..B*S-1
  const int b = row >> 11, s = row & 2047;
  const int t = threadIdx.x;
  const int lane = t & 63, w = t >> 6;
  const uint4* base = (const uint4*)(qkv + (size_t)row * (3 * DD));  // 1536 x uint4

  __shared__ float redsum[8], redss[8];

  uint4 q4[2], k4[2];
  q4[0] = base[t];        q4[1] = base[256 + t];
  k4[0] = base[512 + t];  k4[1] = base[768 + t];

  float qx[16], kx[16];
  unpack8(q4[0], qx); unpack8(q4[1], qx + 8);
  unpack8(k4[0], kx); unpack8(k4[1], kx + 8);

  float qs = 0.f, qss = 0.f, ks = 0.f, kss = 0.f;
  #pragma unroll
  for (int i = 0; i < 16; ++i) {
    qs += qx[i]; qss += qx[i] * qx[i];
    ks += kx[i]; kss += kx[i] * kx[i];
  }
  #pragma unroll
  for (int off = 1; off < 64; off <<= 1) {
    qs  += __shfl_xor(qs, off);  qss += __shfl_xor(qss, off);
    ks  += __shfl_xor(ks, off);  kss += __shfl_xor(kss, off);
  }
  if (lane == 0) { redsum[w] = qs; redss[w] = qss; redsum[4 + w] = ks; redss[4 + w] = kss; }
  __syncthreads();
  float qsum = redsum[0] + redsum[1] + redsum[2] + redsum[3];
  float qs2  = redss[0]  + redss[1]  + redss[2]  + redss[3];
  float ksum = redsum[4] + redsum[5] + redsum[6] + redsum[7];
  float ks2  = redss[4]  + redss[5]  + redss[6]  + redss[7];
  const float inv = 1.0f / (float)DD;
  float qmu = qsum * inv, qvar = qs2 * inv - qmu * qmu;
  float kmu = ksum * inv, kvar = ks2 * inv - kmu * kmu;
  float qrs = rsqrtf(qvar + LN_EPS_);
  float krs = rsqrtf(kvar + LN_EPS_);

  #pragma unroll
  for (int ch = 0; ch < 2; ++ch) {
    int c0 = ch * 2048 + t * 8;
    int hh = c0 >> 7, hd0 = c0 & 127;
    size_t idx = (((size_t)b * HH + hh) * SS + s) * HDD + hd0;
    {
      float4 w0 = *(const float4*)(qw + c0), w1 = *(const float4*)(qw + c0 + 4);
      float4 b0 = *(const float4*)(qb + c0), b1 = *(const float4*)(qb + c0 + 4);
      float wa[8] = {w0.x, w0.y, w0.z, w0.w, w1.x, w1.y, w1.z, w1.w};
      float ba[8] = {b0.x, b0.y, b0.z, b0.w, b1.x, b1.y, b1.z, b1.w};
      u16 tmp[8];
      #pragma unroll
      for (int j = 0; j < 8; ++j)
        tmp[j] = f2bf((qx[ch * 8 + j] - qmu) * qrs * wa[j] + ba[j]);
      *(uint4*)(Qo + idx) = *(const uint4*)tmp;
    }
    {
      float4 w0 = *(const float4*)(kw + c0), w1 = *(const float4*)(kw + c0 + 4);
      float4 b0 = *(const float4*)(kb + c0), b1 = *(const float4*)(kb + c0 + 4);
      float wa[8] = {w0.x, w0.y, w0.z, w0.w, w1.x, w1.y, w1.z, w1.w};
      float ba[8] = {b0.x, b0.y, b0.z, b0.w, b1.x, b1.y, b1.z, b1.w};
      u16 tmp[8];
      #pragma unroll
      for (int j = 0; j < 8; ++j)
        tmp[j] = f2bf((kx[ch * 8 + j] - kmu) * krs * wa[j] + ba[j]);
      *(uint4*)(Ko + idx) = *(const uint4*)tmp;
    }
  }
}

// ---------------- kernel 4b: V slice of qkv -> V^T [B][H][HD][S] ----------------
__global__ void k_transpose_v(const u16* __restrict__ qkv, u16* __restrict__ Vt) {
  __shared__ u16 ls[64 * 65];
  const int s0 = blockIdx.x * 64;
  const int hd0 = blockIdx.y * 64;
  const int bh = blockIdx.z;
  const int b = bh >> 5, h = bh & 31;
  const int t = threadIdx.x;
  const u16* src = qkv + (size_t)(b * SS + s0) * (3 * DD) + 2 * DD + h * HDD + hd0;
  #pragma unroll
  for (int it = 0; it < 4; ++it) {
    int idx = it * 256 + t;
    int sr = idx >> 4, hc = idx & 15;
    uint2 v = *(const uint2*)(src + (size_t)sr * (3 * DD) + hc * 4);
    const u16* pv = (const u16*)&v;
    #pragma unroll
    for (int j = 0; j < 4; ++j) ls[sr * 65 + hc * 4 + j] = pv[j];
  }
  __syncthreads();
  u16* dst = Vt + ((size_t)bh * HDD + hd0) * SS + s0;
  #pragma unroll
  for (int it = 0; it < 4; ++it) {
    int idx = it * 256 + t;
    int hd = idx >> 4, sc = idx & 15;
    u16 tmp[4];
    #pragma unroll
    for (int j = 0; j < 4; ++j) tmp[j] = ls[(4 * sc + j) * 65 + hd];
    *(uint2*)(dst + (size_t)hd * SS + 4 * sc) = *(const uint2*)tmp;
  }
}

// ---------------- kernel 5: flash attention with ALiBi + causal ----------------
// 128-row Q tile x 8 waves; DESCENDING kv iteration (diagonal first) so the
// running max rarely updates -> exact defer-rescale skips the O-rescale.
// Hoisted ALiBi table + wave-uniform unmasked fast path cut the VALU cost.
__global__ __launch_bounds__(512)
void k_attn(const u16* __restrict__ Qg, const u16* __restrict__ Kg,
            const u16* __restrict__ Vt, u16* __restrict__ Og) {
  const int bid = blockIdx.x;               // 1024 blocks
  const int id2 = ((bid & 7) << 7) + (bid >> 3);
  const int bh = id2 >> 4;                  // b*H + h  (8 bh per XCD)
  const int qt = id2 & 15;                  // q tile (128 rows)
  const int b = bh >> 5, h = bh & 31;
  const int t = threadIdx.x;
  const int lane = t & 63, w = t >> 6;      // 8 waves
  const int lg = lane >> 4, lc = lane & 15;
  const float slope = exp2f(-0.25f * (float)(h + 1));

  __shared__ u16 lK[2][8192];               // [64 kv][128 d], 16B granule ^ (row&7)
  __shared__ u16 lV[2][8192];               // V^T [128 hd][64 kv], 16B granule ^ (row&7)
  __shared__ u16 lP[8][1024];               // per-wave P^T: [16 q][64 kv], 8B granule swz

  const int q0 = qt * 128 + w * 16;
  const size_t bhS = (size_t)bh * SS;
  const u16* Kbase = Kg + bhS * HDD;
  const u16* Vbase = Vt + bhS * HDD;        // [128 hd][2048 s] for this bh

  s16x8 qf[4];
  {
    const u16* qrow = Qg + (bhS + q0 + lc) * HDD;
    #pragma unroll
    for (int kt = 0; kt < 4; ++kt) qf[kt] = *(const s16x8*)(qrow + kt * 32 + lg * 8);
  }

  // hoisted ALiBi per-element table: slope * (i*16 + lg*4 + r)
  float sKt[16];
  #pragma unroll
  for (int i = 0; i < 4; ++i)
    #pragma unroll
    for (int r = 0; r < 4; ++r) sKt[i * 4 + r] = slope * (float)(i * 16 + lg * 4 + r);

  f32x4 ot[8];                              // O^T[hd = hf*16 + lg*4 + r][q = lc]
  #pragma unroll
  for (int hf = 0; hf < 8; ++hf) ot[hf] = (f32x4){0.f, 0.f, 0.f, 0.f};
  float m_r = -1e30f, l_r = 0.f;
  const int qg = q0 + lc;

  #define STAGE_KV(D, KV0)                                                         \
    {                                                                              \
      _Pragma("unroll")                                                            \
      for (int it_ = 0; it_ < 2; ++it_) {                                          \
        int sl = it_ * 512 + t;                                                    \
        int row = sl >> 4, k16 = sl & 15;                                          \
        gload_lds16(Kbase + (size_t)((KV0) + row) * HDD + ((k16 ^ (row & 7)) * 8), \
                    &lK[D][sl * 8]);                                               \
      }                                                                            \
      _Pragma("unroll")                                                            \
      for (int it_ = 0; it_ < 2; ++it_) {                                          \
        int sl = it_ * 512 + t;                                                    \
        int row = sl >> 3, k8 = sl & 7;                                            \
        gload_lds16(Vbase + (size_t)row * SS + (KV0) + ((k8 ^ (row & 7)) * 8),     \
                    &lV[D][sl * 8]);                                               \
      }                                                                            \
    }

  const int nt = 2 * qt + 2;
  STAGE_KV((nt - 1) & 1, (nt - 1) * 64)
  __syncthreads();

  for (int itn = nt - 1; itn >= 0; --itn) {
    const int d = itn & 1;
    const int kv0 = itn * 64;
    if (itn > 0) STAGE_KV(d ^ 1, kv0 - 64)

    // wave-uniform skip: this wave's 16 q-rows all < kv0 -> tile fully masked
    if (kv0 <= q0 + 15) {
      // QK^T (swapped): lane holds S^T(kv = i*16 + lg*4 + r, q = lc)
      f32x4 st[4];
      #pragma unroll
      for (int i = 0; i < 4; ++i) {
        st[i] = (f32x4){0.f, 0.f, 0.f, 0.f};
        #pragma unroll
        for (int kt = 0; kt < 4; ++kt) {
          int r = i * 16 + lc;
          const s16x8 ka = *(const s16x8*)&lK[d][r * 128 + (((kt * 4 + lg) ^ (r & 7)) * 8)];
          st[i] = mfma16(ka, qf[kt], st[i]);
        }
      }

      // scores + ALiBi (+ causal mask only on the diagonal tile)
      float sc[4][4];
      float pm = -1e30f;
      const float c0 = slope * (float)(kv0 - qg);
      if (kv0 + 63 <= q0) {
        // fully-unmasked fast path
        #pragma unroll
        for (int i = 0; i < 4; ++i)
          #pragma unroll
          for (int r = 0; r < 4; ++r) {
            float x = fmaf(st[i][r], SCALE_, c0 + sKt[i * 4 + r]);
            sc[i][r] = x;
            pm = fmaxf(pm, x);
          }
      } else {
        const int thr2 = (qg - kv0) - lg * 4;
        #pragma unroll
        for (int i = 0; i < 4; ++i)
          #pragma unroll
          for (int r = 0; r < 4; ++r) {
            float x = ((i * 16 + r) <= thr2)
                          ? fmaf(st[i][r], SCALE_, c0 + sKt[i * 4 + r])
                          : -1e30f;
            sc[i][r] = x;
            pm = fmaxf(pm, x);
          }
      }
      pm = fmaxf(pm, __shfl_xor(pm, 16));
      pm = fmaxf(pm, __shfl_xor(pm, 32));

      // exact defer-rescale: only when some lane's max grew
      if (__any(pm > m_r)) {
        float m_new = fmaxf(m_r, pm);
        float alpha = exp2f((m_r - m_new) * LOG2E_);
        #pragma unroll
        for (int hf = 0; hf < 8; ++hf) {
          ot[hf][0] *= alpha; ot[hf][1] *= alpha; ot[hf][2] *= alpha; ot[hf][3] *= alpha;
        }
        l_r *= alpha;
        m_r = m_new;
      }

      float rsum = 0.f;
      #pragma unroll
      for (int i = 0; i < 4; ++i) {
        float p0 = exp2f((sc[i][0] - m_r) * LOG2E_);
        float p1 = exp2f((sc[i][1] - m_r) * LOG2E_);
        float p2 = exp2f((sc[i][2] - m_r) * LOG2E_);
        float p3 = exp2f((sc[i][3] - m_r) * LOG2E_);
        rsum += (p0 + p1) + (p2 + p3);
        u32 dlo, dhi;
        asm("v_cvt_pk_bf16_f32 %0, %1, %2" : "=v"(dlo) : "v"(p0), "v"(p1));
        asm("v_cvt_pk_bf16_f32 %0, %1, %2" : "=v"(dhi) : "v"(p2), "v"(p3));
        int addr = lc * 64 + (((4 * i + lg) ^ (2 * (lc & 7))) * 4);
        uint2 val; val.x = dlo; val.y = dhi;
        *(uint2*)&lP[w][addr] = val;
      }
      rsum += __shfl_xor(rsum, 16);
      rsum += __shfl_xor(rsum, 32);
      l_r += rsum;

      // PV: O^T[hd][q] += V^T[hd][kv] * P^T[kv][q]
      #pragma unroll
      for (int ks = 0; ks < 2; ++ks) {
        const int m = 4 * ks + lg;            // 16B granule along kv
        const s16x8 pa = *(const s16x8*)&lP[w][lc * 64 + ((m ^ (lc & 7)) * 8)];
        #pragma unroll
        for (int hf = 0; hf < 8; ++hf) {
          int row = hf * 16 + lc;
          const s16x8 vb = *(const s16x8*)&lV[d][row * 64 + ((m ^ (row & 7)) * 8)];
          ot[hf] = mfma16(vb, pa, ot[hf]);
        }
      }
    }
    __syncthreads();   // drains vmcnt(0) too -> next-tile staging complete
  }
  #undef STAGE_KV

  // epilogue: normalize by l (lane-local), store 8B chunks (4 contiguous hd)
  float linv = 1.f / l_r;
  const size_t obase = ((size_t)(b * SS + q0 + lc)) * DD + h * HDD;
  #pragma unroll
  for (int hf = 0; hf < 8; ++hf) {
    u16 tmp[4];
    #pragma unroll
    for (int r = 0; r < 4; ++r) tmp[r] = f2bf(ot[hf][r] * linv);
    *(uint2*)&Og[obase + hf * 16 + lg * 4] = *(const uint2*)tmp;
  }
}

// ---------------- launch ----------------
extern "C" void kernel_launch(void* const* d_in, const int* in_sizes, int n_in,
                              void* d_out, int out_size, void* d_ws, size_t ws_size,
                              hipStream_t stream) {
  const float* hidden = (const float*)d_in[0];
  const float* Wqkv   = (const float*)d_in[1];
  const float* Wout   = (const float*)d_in[2];
  const float* qw     = (const float*)d_in[3];
  const float* qb     = (const float*)d_in[4];
  const float* kw     = (const float*)d_in[5];
  const float* kb     = (const float*)d_in[6];
  float* out = (float*)d_out;
  char* ws = (char*)d_ws;

  // workspace layout (total 256 MB)
  u16* Xb    = (u16*)(ws);                    // 32 MB (reused as attn_out)
  u16* WqkvT = (u16*)(ws + 33554432);         // 96 MB (reused as Q,K,Vt after GEMM)
  u16* Qb    = (u16*)(ws + 33554432);
  u16* Kb    = (u16*)(ws + 67108864);
  u16* Vtb   = (u16*)(ws + 100663296);        // V^T [B][H][HD][S]
  u16* WoutT = (u16*)(ws + 134217728);        // 32 MB
  u16* qkv   = (u16*)(ws + 167772160);        // 96 MB
  u16* attnO = Xb;

  k_cvt_bf16<<<8192, 256, 0, stream>>>(hidden, Xb, 2097152);
  k_transpose_cvt<<<dim3(12288 / 32, 4096 / 32), 256, 0, stream>>>(Wqkv, WqkvT, 4096, 12288);
  k_transpose_cvt<<<dim3(4096 / 32, 4096 / 32), 256, 0, stream>>>(Wout, WoutT, 4096, 4096);
  // QKV GEMM: M=4096, N=12288, K=4096 -> grid 768, nBY=16
  k_gemm256<0><<<768, 512, 0, stream>>>(Xb, WqkvT, qkv, 4096, 12288, 4096, 16);
  k_ln_reorder<<<4096, 256, 0, stream>>>(qkv, qw, qb, kw, kb, Qb, Kb);
  k_transpose_v<<<dim3(SS / 64, HDD / 64, BB * HH), 256, 0, stream>>>(qkv, Vtb);
  // attention: 64 bh x 16 q-tiles(128 rows) = 1024 blocks, 512 threads
  k_attn<<<1024, 512, 0, stream>>>(Qb, Kb, Vtb, attnO);
  // out-proj GEMM: M=4096, N=4096, K=4096 -> grid 256, nBY=16
  k_gemm256<1><<<256, 512, 0, stream>>>(attnO, WoutT, out, 4096, 4096, 4096, 16);
}

// Round 12
// 792.448 us; speedup vs baseline: 1.4942x; 1.4942x over previous
//
#include <hip/hip_runtime.h>
#include <hip/hip_bf16.h>
#include <stdint.h>

// Problem constants
#define BB 2
#define SS 2048
#define DD 4096
#define HH 32
#define HDD 128

typedef unsigned short u16;
typedef unsigned int u32;

constexpr float CLIPV  = 8.0f;
constexpr float LN_EPS_ = 1e-5f;
constexpr float SCALE_ = 0.08838834764831845f;   // 1/sqrt(128)
constexpr float LOG2E_ = 1.4426950408889634f;

using f32x4 = __attribute__((ext_vector_type(4))) float;
using s16x8 = __attribute__((ext_vector_type(8))) short;

__device__ inline u16 f2bf(float f) {
  union { float f; u32 u; } v; v.f = f;
  u32 r = (v.u + 0x7FFFu + ((v.u >> 16) & 1u)) >> 16;
  return (u16)r;
}
__device__ inline float bf2f(u16 u) {
  union { u32 u; float f; } v; v.u = ((u32)u) << 16;
  return v.f;
}

typedef __attribute__((address_space(1))) void gvoid;
typedef __attribute__((address_space(3))) void lvoid;
__device__ inline void gload_lds16(const void* g, void* l) {
  __builtin_amdgcn_global_load_lds((gvoid*)g, (lvoid*)l, 16, 0, 0);
}

__device__ inline f32x4 mfma16(s16x8 a, s16x8 b, f32x4 c) {
  return __builtin_amdgcn_mfma_f32_16x16x32_bf16(a, b, c, 0, 0, 0);
}

// ---------------- kernel 1: f32 -> bf16 elementwise ----------------
__global__ void k_cvt_bf16(const float* __restrict__ in, u16* __restrict__ out, int nvec) {
  int i = blockIdx.x * 256 + threadIdx.x;
  if (i >= nvec) return;
  float4 a = ((const float4*)in)[i * 2];
  float4 b = ((const float4*)in)[i * 2 + 1];
  u16 tmp[8];
  tmp[0] = f2bf(a.x); tmp[1] = f2bf(a.y); tmp[2] = f2bf(a.z); tmp[3] = f2bf(a.w);
  tmp[4] = f2bf(b.x); tmp[5] = f2bf(b.y); tmp[6] = f2bf(b.z); tmp[7] = f2bf(b.w);
  ((uint4*)out)[i] = *(const uint4*)tmp;
}

// ---------------- kernel 2: transpose + convert: src f32 [R][C] -> dst bf16 [C][R] ----------------
__global__ void k_transpose_cvt(const float* __restrict__ src, u16* __restrict__ dst, int R, int C) {
  __shared__ float tile[32][33];
  int c0 = blockIdx.x * 32, r0 = blockIdx.y * 32;
  int tx = threadIdx.x & 31, ty = threadIdx.x >> 5;   // 32 x 8
  #pragma unroll
  for (int i = 0; i < 32; i += 8)
    tile[ty + i][tx] = src[(size_t)(r0 + ty + i) * C + (c0 + tx)];
  __syncthreads();
  #pragma unroll
  for (int i = 0; i < 32; i += 8)
    dst[(size_t)(c0 + ty + i) * R + (r0 + tx)] = f2bf(tile[tx][ty + i]);
}

// ---------------- 256x256 GEMM with asm ds_read + counted lgkm (round-8 winner, reverted) ----
// 16x16x32 MFMA; compiler-invisible ds_read_b128 issued one phase ahead with
// hand-counted lgkmcnt -> LDS pipe overlaps MFMA. 0 bank conflicts measured.
__device__ __forceinline__ void stage_half(u16* ldsHalf, const u16* g, int K, int tid) {
  #pragma unroll
  for (int it = 0; it < 2; ++it) {
    int p = (it << 9) + tid;           // 16B slot index 0..1023
    int row = p >> 3;                  // 0..127
    int slotk = (p & 7) ^ (row & 7);   // inverse-swizzled source slot
    gload_lds16(g + (size_t)row * K + (slotk << 3), ldsHalf + ((size_t)p << 3));
  }
}

#define DSR(dst, adr, IMM) \
  asm volatile("ds_read_b128 %0, %1 offset:" #IMM : "=v"(dst) : "v"(adr) : "memory")

#define RD_B1(a0, a1)            \
  DSR(bB_[0][0], a0, 4096);      \
  DSR(bB_[0][1], a1, 4096);      \
  DSR(bB_[1][0], a0, 6144);      \
  DSR(bB_[1][1], a1, 6144);

#define RD_A1(a0, a1)            \
  DSR(aN[0][0], a0, 8192);       \
  DSR(aN[0][1], a1, 8192);       \
  DSR(aN[1][0], a0, 10240);      \
  DSR(aN[1][1], a1, 10240);      \
  DSR(aN[2][0], a0, 12288);      \
  DSR(aN[2][1], a1, 12288);      \
  DSR(aN[3][0], a0, 14336);      \
  DSR(aN[3][1], a1, 14336);

#define RD_A0(a0, a1)            \
  DSR(aC[0][0], a0, 0);          \
  DSR(aC[0][1], a1, 0);          \
  DSR(aC[1][0], a0, 2048);       \
  DSR(aC[1][1], a1, 2048);       \
  DSR(aC[2][0], a0, 4096);       \
  DSR(aC[2][1], a1, 4096);       \
  DSR(aC[3][0], a0, 6144);       \
  DSR(aC[3][1], a1, 6144);

#define RD_B0(a0, a1)            \
  DSR(bA_[0][0], a0, 0);         \
  DSR(bA_[0][1], a1, 0);         \
  DSR(bA_[1][0], a0, 2048);      \
  DSR(bA_[1][1], a1, 2048);

#define LGKM(N)                                                    \
  asm volatile("s_waitcnt lgkmcnt(" #N ")" ::: "memory");          \
  __builtin_amdgcn_sched_barrier(0);

#define MQ(AF, BF, MB, JB)                                                    \
  _Pragma("unroll")                                                           \
  for (int i_ = 0; i_ < 4; ++i_) {                                            \
    _Pragma("unroll")                                                         \
    for (int jj_ = 0; jj_ < 2; ++jj_) {                                       \
      acc[(MB) + i_][(JB) + jj_] =                                            \
          mfma16(AF[i_][0], BF[jj_][0], acc[(MB) + i_][(JB) + jj_]);          \
      acc[(MB) + i_][(JB) + jj_] =                                            \
          mfma16(AF[i_][1], BF[jj_][1], acc[(MB) + i_][(JB) + jj_]);          \
    }                                                                         \
  }

template <int EPI>   // 0: clip to +-8, store bf16 ; 1: store f32
__launch_bounds__(512)
__global__ void k_gemm256(const u16* __restrict__ A, const u16* __restrict__ Bt,
                          void* __restrict__ Cout, int M, int N, int K, int nBY) {
  __shared__ u16 lds[65536];            // A: [0,32768) u16 ; B: [32768,65536) u16
  u16* sA = lds;
  u16* sB = lds + 32768;
  const int tid = threadIdx.x;
  const int lane = tid & 63, w = tid >> 6;
  const int wm = w >> 2, wn = w & 3;          // 2 x 4 waves
  const int lg = lane >> 4, lc = lane & 15;

  // column-major-within-XCD bijective swizzle (nwg % 8 == 0)
  const int nwg = gridDim.x;
  const int cpx = nwg >> 3;
  const int id2 = (blockIdx.x & 7) * cpx + (blockIdx.x >> 3);
  const int bx = id2 / nBY, by = id2 % nBY;
  const int m0 = by * 256, n0 = bx * 256;

  const int NT = K >> 6;
  const u16* gA = A  + (size_t)m0 * K;
  const u16* gB = Bt + (size_t)n0 * K;

  const int xt0 = ((lg) ^ (lc & 7)) * 8;        // u16 units
  const int rowoff = lc * 64;

  // byte addresses for asm ds_read (buf0); buf toggle = ^32768
  const u32 aBase0 = (u32)(2 * (wm * 8192 + rowoff + xt0));
  const u32 bBase0 = (u32)(2 * (32768 + (wn >> 1) * 8192 + (wn & 1) * 4096 + rowoff + xt0));

  f32x4 acc[8][4];
  #pragma unroll
  for (int i = 0; i < 8; ++i)
    #pragma unroll
    for (int j = 0; j < 4; ++j) acc[i][j] = (f32x4){0.f, 0.f, 0.f, 0.f};

  // ---- prologue: 7 half-tiles; drain; pre-issue A0(0),B0(0) reads ----
  stage_half(sA,         gA,                        K, tid);  // Ah0(0)
  stage_half(sA + 8192,  gA + (size_t)128 * K,      K, tid);  // Ah1(0)
  stage_half(sB,         gB,                        K, tid);  // Bh0(0)
  stage_half(sB + 8192,  gB + (size_t)128 * K,      K, tid);  // Bh1(0)
  stage_half(sB + 16384, gB + 64,                   K, tid);  // Bh0(1)
  stage_half(sB + 24576, gB + (size_t)128 * K + 64, K, tid);  // Bh1(1)
  stage_half(sA + 24576, gA + (size_t)128 * K + 64, K, tid);  // Ah1(1)
  asm volatile("s_waitcnt vmcnt(0)" ::: "memory");
  __builtin_amdgcn_s_barrier();

  s16x8 aC[4][2], aN[4][2], bA_[2][2], bB_[2][2];
  {
    u32 a0 = aBase0, a1 = aBase0 ^ 64;
    u32 b0 = bBase0, b1 = bBase0 ^ 64;
    RD_A0(a0, a1)         // A0(0) -> aC  [8 reads]
    RD_B0(b0, b1)         // B0(0) -> bA_ [4 reads]
  }

  for (int t = 0; t < NT; ++t) {
    const int d = t & 1;
    const bool m1 = (t + 1 < NT);
    const bool m2 = (t + 2 < NT);
    const u32 dx = d ? 32768u : 0u;
    const u32 a0 = aBase0 ^ dx, a1 = a0 ^ 64;
    const u32 b0 = bBase0 ^ dx, b1 = b0 ^ 64;
    const u32 an0 = a0 ^ 32768u, an1 = a1 ^ 32768u;
    const u32 bn0 = b0 ^ 32768u, bn1 = b1 ^ 32768u;

    // ---------- P1: issue B1(t); stage Ah0(t+1); wait(4); Q1 = A0 x B0 ----------
    RD_B1(b0, b1)
    if (m1) stage_half(sA + (d ^ 1) * 16384, gA + (size_t)(t + 1) * 64, K, tid);
    LGKM(4)
    __builtin_amdgcn_s_setprio(1);
    MQ(aC, bA_, 0, 0)
    __builtin_amdgcn_s_setprio(0);
    __builtin_amdgcn_s_barrier();

    // ---------- P2: issue A1(t); stage Bh0(t+2); wait(8); Q2 = A0 x B1 ----------
    RD_A1(a0, a1)
    if (m2) stage_half(sB + d * 16384, gB + (size_t)(t + 2) * 64, K, tid);
    LGKM(8)
    __builtin_amdgcn_s_setprio(1);
    MQ(aC, bB_, 0, 2)
    __builtin_amdgcn_s_setprio(0);
    __builtin_amdgcn_s_barrier();

    // ---------- P3: stage Bh1(t+2); wait(0); Q3 = A1 x B0; gate vmcnt(4) ----------
    if (m2) stage_half(sB + d * 16384 + 8192, gB + (size_t)128 * K + (size_t)(t + 2) * 64, K, tid);
    LGKM(0)
    __builtin_amdgcn_s_setprio(1);
    MQ(aN, bA_, 4, 0)
    __builtin_amdgcn_s_setprio(0);
    if (m2) { asm volatile("s_waitcnt vmcnt(4)" ::: "memory"); }
    else    { asm volatile("s_waitcnt vmcnt(0)" ::: "memory"); }
    __builtin_amdgcn_s_barrier();

    // ---------- P4: issue A0,B0(t+1); stage Ah1(t+2); Q4 = A1 x B1; gate vmcnt(2) ----------
    if (m1) {
      RD_A0(an0, an1)
      RD_B0(bn0, bn1)
      if (m2) stage_half(sA + d * 16384 + 8192, gA + (size_t)128 * K + (size_t)(t + 2) * 64, K, tid);
    }
    __builtin_amdgcn_sched_barrier(0);
    __builtin_amdgcn_s_setprio(1);
    MQ(aN, bB_, 4, 2)
    __builtin_amdgcn_s_setprio(0);
    if (m2) { asm volatile("s_waitcnt vmcnt(2)" ::: "memory"); }
    else    { asm volatile("s_waitcnt vmcnt(0)" ::: "memory"); }
    __builtin_amdgcn_s_barrier();
  }

  #pragma unroll
  for (int i = 0; i < 8; ++i)
    #pragma unroll
    for (int j = 0; j < 4; ++j)
      #pragma unroll
      for (int r = 0; r < 4; ++r) {
        int m = m0 + wm * 128 + i * 16 + lg * 4 + r;
        int n = n0 + wn * 64 + j * 16 + lc;
        float v = acc[i][j][r];
        if (EPI == 0) {
          v = fminf(fmaxf(v, -CLIPV), CLIPV);
          ((u16*)Cout)[(size_t)m * N + n] = f2bf(v);
        } else {
          ((float*)Cout)[(size_t)m * N + n] = v;
        }
      }
}

// ---------------- kernel 4: LN(q), LN(k) over D=4096 + head relayout of q,k ----------------
__device__ inline void unpack8(uint4 u, float* f) {
  const u16* p = (const u16*)&u;
  #pragma unroll
  for (int j = 0; j < 8; ++j) f[j] = bf2f(p[j]);
}

__global__ void k_ln_reorder(const u16* __restrict__ qkv,
                             const float* __restrict__ qw, const float* __restrict__ qb,
                             const float* __restrict__ kw, const float* __restrict__ kb,
                             u16* __restrict__ Qo, u16* __restrict__ Ko) {
  const int row = blockIdx.x;               // 0..B*S-1
  const int b = row >> 11, s = row & 2047;
  const int t = threadIdx.x;
  const int lane = t & 63, w = t >> 6;
  const uint4* base = (const uint4*)(qkv + (size_t)row * (3 * DD));  // 1536 x uint4

  __shared__ float redsum[8], redss[8];

  uint4 q4[2], k4[2];
  q4[0] = base[t];        q4[1] = base[256 + t];
  k4[0] = base[512 + t];  k4[1] = base[768 + t];

  float qx[16], kx[16];
  unpack8(q4[0], qx); unpack8(q4[1], qx + 8);
  unpack8(k4[0], kx); unpack8(k4[1], kx + 8);

  float qs = 0.f, qss = 0.f, ks = 0.f, kss = 0.f;
  #pragma unroll
  for (int i = 0; i < 16; ++i) {
    qs += qx[i]; qss += qx[i] * qx[i];
    ks += kx[i]; kss += kx[i] * kx[i];
  }
  #pragma unroll
  for (int off = 1; off < 64; off <<= 1) {
    qs  += __shfl_xor(qs, off);  qss += __shfl_xor(qss, off);
    ks  += __shfl_xor(ks, off);  kss += __shfl_xor(kss, off);
  }
  if (lane == 0) { redsum[w] = qs; redss[w] = qss; redsum[4 + w] = ks; redss[4 + w] = kss; }
  __syncthreads();
  float qsum = redsum[0] + redsum[1] + redsum[2] + redsum[3];
  float qs2  = redss[0]  + redss[1]  + redss[2]  + redss[3];
  float ksum = redsum[4] + redsum[5] + redsum[6] + redsum[7];
  float ks2  = redss[4]  + redss[5]  + redss[6]  + redss[7];
  const float inv = 1.0f / (float)DD;
  float qmu = qsum * inv, qvar = qs2 * inv - qmu * qmu;
  float kmu = ksum * inv, kvar = ks2 * inv - kmu * kmu;
  float qrs = rsqrtf(qvar + LN_EPS_);
  float krs = rsqrtf(kvar + LN_EPS_);

  #pragma unroll
  for (int ch = 0; ch < 2; ++ch) {
    int c0 = ch * 2048 + t * 8;
    int hh = c0 >> 7, hd0 = c0 & 127;
    size_t idx = (((size_t)b * HH + hh) * SS + s) * HDD + hd0;
    {
      float4 w0 = *(const float4*)(qw + c0), w1 = *(const float4*)(qw + c0 + 4);
      float4 b0 = *(const float4*)(qb + c0), b1 = *(const float4*)(qb + c0 + 4);
      float wa[8] = {w0.x, w0.y, w0.z, w0.w, w1.x, w1.y, w1.z, w1.w};
      float ba[8] = {b0.x, b0.y, b0.z, b0.w, b1.x, b1.y, b1.z, b1.w};
      u16 tmp[8];
      #pragma unroll
      for (int j = 0; j < 8; ++j)
        tmp[j] = f2bf((qx[ch * 8 + j] - qmu) * qrs * wa[j] + ba[j]);
      *(uint4*)(Qo + idx) = *(const uint4*)tmp;
    }
    {
      float4 w0 = *(const float4*)(kw + c0), w1 = *(const float4*)(kw + c0 + 4);
      float4 b0 = *(const float4*)(kb + c0), b1 = *(const float4*)(kb + c0 + 4);
      float wa[8] = {w0.x, w0.y, w0.z, w0.w, w1.x, w1.y, w1.z, w1.w};
      float ba[8] = {b0.x, b0.y, b0.z, b0.w, b1.x, b1.y, b1.z, b1.w};
      u16 tmp[8];
      #pragma unroll
      for (int j = 0; j < 8; ++j)
        tmp[j] = f2bf((kx[ch * 8 + j] - kmu) * krs * wa[j] + ba[j]);
      *(uint4*)(Ko + idx) = *(const uint4*)tmp;
    }
  }
}

// ---------------- kernel 4b: V slice of qkv -> V^T [B][H][HD][S] ----------------
__global__ void k_transpose_v(const u16* __restrict__ qkv, u16* __restrict__ Vt) {
  __shared__ u16 ls[64 * 65];
  const int s0 = blockIdx.x * 64;
  const int hd0 = blockIdx.y * 64;
  const int bh = blockIdx.z;
  const int b = bh >> 5, h = bh & 31;
  const int t = threadIdx.x;
  const u16* src = qkv + (size_t)(b * SS + s0) * (3 * DD) + 2 * DD + h * HDD + hd0;
  #pragma unroll
  for (int it = 0; it < 4; ++it) {
    int idx = it * 256 + t;
    int sr = idx >> 4, hc = idx & 15;
    uint2 v = *(const uint2*)(src + (size_t)sr * (3 * DD) + hc * 4);
    const u16* pv = (const u16*)&v;
    #pragma unroll
    for (int j = 0; j < 4; ++j) ls[sr * 65 + hc * 4 + j] = pv[j];
  }
  __syncthreads();
  u16* dst = Vt + ((size_t)bh * HDD + hd0) * SS + s0;
  #pragma unroll
  for (int it = 0; it < 4; ++it) {
    int idx = it * 256 + t;
    int hd = idx >> 4, sc = idx & 15;
    u16 tmp[4];
    #pragma unroll
    for (int j = 0; j < 4; ++j) tmp[j] = ls[(4 * sc + j) * 65 + hd];
    *(uint2*)(dst + (size_t)hd * SS + 4 * sc) = *(const uint2*)tmp;
  }
}

// ---------------- kernel 5: flash attention with ALiBi + causal ----------------
// 128-row Q tile x 8 waves; DESCENDING kv iteration (diagonal first) so the
// running max rarely updates -> exact defer-rescale skips the O-rescale.
// Hoisted ALiBi table + wave-uniform unmasked fast path cut the VALU cost.
__global__ __launch_bounds__(512)
void k_attn(const u16* __restrict__ Qg, const u16* __restrict__ Kg,
            const u16* __restrict__ Vt, u16* __restrict__ Og) {
  const int bid = blockIdx.x;               // 1024 blocks
  const int id2 = ((bid & 7) << 7) + (bid >> 3);
  const int bh = id2 >> 4;                  // b*H + h  (8 bh per XCD)
  const int qt = id2 & 15;                  // q tile (128 rows)
  const int b = bh >> 5, h = bh & 31;
  const int t = threadIdx.x;
  const int lane = t & 63, w = t >> 6;      // 8 waves
  const int lg = lane >> 4, lc = lane & 15;
  const float slope = exp2f(-0.25f * (float)(h + 1));

  __shared__ u16 lK[2][8192];               // [64 kv][128 d], 16B granule ^ (row&7)
  __shared__ u16 lV[2][8192];               // V^T [128 hd][64 kv], 16B granule ^ (row&7)
  __shared__ u16 lP[8][1024];               // per-wave P^T: [16 q][64 kv], 8B granule swz

  const int q0 = qt * 128 + w * 16;
  const size_t bhS = (size_t)bh * SS;
  const u16* Kbase = Kg + bhS * HDD;
  const u16* Vbase = Vt + bhS * HDD;        // [128 hd][2048 s] for this bh

  s16x8 qf[4];
  {
    const u16* qrow = Qg + (bhS + q0 + lc) * HDD;
    #pragma unroll
    for (int kt = 0; kt < 4; ++kt) qf[kt] = *(const s16x8*)(qrow + kt * 32 + lg * 8);
  }

  // hoisted ALiBi per-element table: slope * (i*16 + lg*4 + r)
  float sKt[16];
  #pragma unroll
  for (int i = 0; i < 4; ++i)
    #pragma unroll
    for (int r = 0; r < 4; ++r) sKt[i * 4 + r] = slope * (float)(i * 16 + lg * 4 + r);

  f32x4 ot[8];                              // O^T[hd = hf*16 + lg*4 + r][q = lc]
  #pragma unroll
  for (int hf = 0; hf < 8; ++hf) ot[hf] = (f32x4){0.f, 0.f, 0.f, 0.f};
  float m_r = -1e30f, l_r = 0.f;
  const int qg = q0 + lc;

  #define STAGE_KV(D, KV0)                                                         \
    {                                                                              \
      _Pragma("unroll")                                                            \
      for (int it_ = 0; it_ < 2; ++it_) {                                          \
        int sl = it_ * 512 + t;                                                    \
        int row = sl >> 4, k16 = sl & 15;                                          \
        gload_lds16(Kbase + (size_t)((KV0) + row) * HDD + ((k16 ^ (row & 7)) * 8), \
                    &lK[D][sl * 8]);                                               \
      }                                                                            \
      _Pragma("unroll")                                                            \
      for (int it_ = 0; it_ < 2; ++it_) {                                          \
        int sl = it_ * 512 + t;                                                    \
        int row = sl >> 3, k8 = sl & 7;                                            \
        gload_lds16(Vbase + (size_t)row * SS + (KV0) + ((k8 ^ (row & 7)) * 8),     \
                    &lV[D][sl * 8]);                                               \
      }                                                                            \
    }

  const int nt = 2 * qt + 2;
  STAGE_KV((nt - 1) & 1, (nt - 1) * 64)
  __syncthreads();

  for (int itn = nt - 1; itn >= 0; --itn) {
    const int d = itn & 1;
    const int kv0 = itn * 64;
    if (itn > 0) STAGE_KV(d ^ 1, kv0 - 64)

    // wave-uniform skip: this wave's 16 q-rows all < kv0 -> tile fully masked
    if (kv0 <= q0 + 15) {
      // QK^T (swapped): lane holds S^T(kv = i*16 + lg*4 + r, q = lc)
      f32x4 st[4];
      #pragma unroll
      for (int i = 0; i < 4; ++i) {
        st[i] = (f32x4){0.f, 0.f, 0.f, 0.f};
        #pragma unroll
        for (int kt = 0; kt < 4; ++kt) {
          int r = i * 16 + lc;
          const s16x8 ka = *(const s16x8*)&lK[d][r * 128 + (((kt * 4 + lg) ^ (r & 7)) * 8)];
          st[i] = mfma16(ka, qf[kt], st[i]);
        }
      }

      // scores + ALiBi (+ causal mask only on the diagonal tile)
      float sc[4][4];
      float pm = -1e30f;
      const float c0 = slope * (float)(kv0 - qg);
      if (kv0 + 63 <= q0) {
        // fully-unmasked fast path
        #pragma unroll
        for (int i = 0; i < 4; ++i)
          #pragma unroll
          for (int r = 0; r < 4; ++r) {
            float x = fmaf(st[i][r], SCALE_, c0 + sKt[i * 4 + r]);
            sc[i][r] = x;
            pm = fmaxf(pm, x);
          }
      } else {
        const int thr2 = (qg - kv0) - lg * 4;
        #pragma unroll
        for (int i = 0; i < 4; ++i)
          #pragma unroll
          for (int r = 0; r < 4; ++r) {
            float x = ((i * 16 + r) <= thr2)
                          ? fmaf(st[i][r], SCALE_, c0 + sKt[i * 4 + r])
                          : -1e30f;
            sc[i][r] = x;
            pm = fmaxf(pm, x);
          }
      }
      pm = fmaxf(pm, __shfl_xor(pm, 16));
      pm = fmaxf(pm, __shfl_xor(pm, 32));

      // exact defer-rescale: only when some lane's max grew
      if (__any(pm > m_r)) {
        float m_new = fmaxf(m_r, pm);
        float alpha = exp2f((m_r - m_new) * LOG2E_);
        #pragma unroll
        for (int hf = 0; hf < 8; ++hf) {
          ot[hf][0] *= alpha; ot[hf][1] *= alpha; ot[hf][2] *= alpha; ot[hf][3] *= alpha;
        }
        l_r *= alpha;
        m_r = m_new;
      }

      float rsum = 0.f;
      #pragma unroll
      for (int i = 0; i < 4; ++i) {
        float p0 = exp2f((sc[i][0] - m_r) * LOG2E_);
        float p1 = exp2f((sc[i][1] - m_r) * LOG2E_);
        float p2 = exp2f((sc[i][2] - m_r) * LOG2E_);
        float p3 = exp2f((sc[i][3] - m_r) * LOG2E_);
        rsum += (p0 + p1) + (p2 + p3);
        u32 dlo, dhi;
        asm("v_cvt_pk_bf16_f32 %0, %1, %2" : "=v"(dlo) : "v"(p0), "v"(p1));
        asm("v_cvt_pk_bf16_f32 %0, %1, %2" : "=v"(dhi) : "v"(p2), "v"(p3));
        int addr = lc * 64 + (((4 * i + lg) ^ (2 * (lc & 7))) * 4);
        uint2 val; val.x = dlo; val.y = dhi;
        *(uint2*)&lP[w][addr] = val;
      }
      rsum += __shfl_xor(rsum, 16);
      rsum += __shfl_xor(rsum, 32);
      l_r += rsum;

      // PV: O^T[hd][q] += V^T[hd][kv] * P^T[kv][q]
      #pragma unroll
      for (int ks = 0; ks < 2; ++ks) {
        const int m = 4 * ks + lg;            // 16B granule along kv
        const s16x8 pa = *(const s16x8*)&lP[w][lc * 64 + ((m ^ (lc & 7)) * 8)];
        #pragma unroll
        for (int hf = 0; hf < 8; ++hf) {
          int row = hf * 16 + lc;
          const s16x8 vb = *(const s16x8*)&lV[d][row * 64 + ((m ^ (row & 7)) * 8)];
          ot[hf] = mfma16(vb, pa, ot[hf]);
        }
      }
    }
    __syncthreads();   // drains vmcnt(0) too -> next-tile staging complete
  }
  #undef STAGE_KV

  // epilogue: normalize by l (lane-local), store 8B chunks (4 contiguous hd)
  float linv = 1.f / l_r;
  const size_t obase = ((size_t)(b * SS + q0 + lc)) * DD + h * HDD;
  #pragma unroll
  for (int hf = 0; hf < 8; ++hf) {
    u16 tmp[4];
    #pragma unroll
    for (int r = 0; r < 4; ++r) tmp[r] = f2bf(ot[hf][r] * linv);
    *(uint2*)&Og[obase + hf * 16 + lg * 4] = *(const uint2*)tmp;
  }
}

// ---------------- launch ----------------
extern "C" void kernel_launch(void* const* d_in, const int* in_sizes, int n_in,
                              void* d_out, int out_size, void* d_ws, size_t ws_size,
                              hipStream_t stream) {
  const float* hidden = (const float*)d_in[0];
  const float* Wqkv   = (const float*)d_in[1];
  const float* Wout   = (const float*)d_in[2];
  const float* qw     = (const float*)d_in[3];
  const float* qb     = (const float*)d_in[4];
  const float* kw     = (const float*)d_in[5];
  const float* kb     = (const float*)d_in[6];
  float* out = (float*)d_out;
  char* ws = (char*)d_ws;

  // workspace layout (total 256 MB)
  u16* Xb    = (u16*)(ws);                    // 32 MB (reused as attn_out)
  u16* WqkvT = (u16*)(ws + 33554432);         // 96 MB (reused as Q,K,Vt after GEMM)
  u16* Qb    = (u16*)(ws + 33554432);
  u16* Kb    = (u16*)(ws + 67108864);
  u16* Vtb   = (u16*)(ws + 100663296);        // V^T [B][H][HD][S]
  u16* WoutT = (u16*)(ws + 134217728);        // 32 MB
  u16* qkv   = (u16*)(ws + 167772160);        // 96 MB
  u16* attnO = Xb;

  k_cvt_bf16<<<8192, 256, 0, stream>>>(hidden, Xb, 2097152);
  k_transpose_cvt<<<dim3(12288 / 32, 4096 / 32), 256, 0, stream>>>(Wqkv, WqkvT, 4096, 12288);
  k_transpose_cvt<<<dim3(4096 / 32, 4096 / 32), 256, 0, stream>>>(Wout, WoutT, 4096, 4096);
  // QKV GEMM: M=4096, N=12288, K=4096 -> grid 768, nBY=16
  k_gemm256<0><<<768, 512, 0, stream>>>(Xb, WqkvT, qkv, 4096, 12288, 4096, 16);
  k_ln_reorder<<<4096, 256, 0, stream>>>(qkv, qw, qb, kw, kb, Qb, Kb);
  k_transpose_v<<<dim3(SS / 64, HDD / 64, BB * HH), 256, 0, stream>>>(qkv, Vtb);
  // attention: 64 bh x 16 q-tiles(128 rows) = 1024 blocks, 512 threads
  k_attn<<<1024, 512, 0, stream>>>(Qb, Kb, Vtb, attnO);
  // out-proj GEMM: M=4096, N=4096, K=4096 -> grid 256, nBY=16
  k_gemm256<1><<<256, 512, 0, stream>>>(attnO, WoutT, out, 4096, 4096, 4096, 16);
}